// Round 3
// baseline (1741.185 us; speedup 1.0000x reference)
//
#include <hip/hip_runtime.h>
#include <hip/hip_bf16.h>

#define SEQ 1024
#define DM 512
#define D2 1024
#define NSTATE 16
#define BATCH 8
#define ROWS (BATCH * SEQ)
#define EPSF 1e-5f

#define EPI_NONE 0
#define EPI_SILU 1
#define EPI_SSM 2
#define EPI_OUT 3

__device__ __forceinline__ float sigmoidf_(float x) {
    return 1.f / (1.f + __expf(-x));
}

// ---------------------------------------------------------------- rmsnorm
__global__ __launch_bounds__(256) void rmsnorm_k(
    const float* __restrict__ x, const float* __restrict__ w,
    float* __restrict__ o) {
    int row = blockIdx.x;
    const float* xr = x + (size_t)row * DM;
    float* orow = o + (size_t)row * DM;
    int t = threadIdx.x;
    float v0 = xr[t];
    float v1 = xr[t + 256];
    float ss = v0 * v0 + v1 * v1;
#pragma unroll
    for (int off = 32; off; off >>= 1) ss += __shfl_down(ss, off, 64);
    __shared__ float parts[4];
    if ((t & 63) == 0) parts[t >> 6] = ss;
    __syncthreads();
    float tot = parts[0] + parts[1] + parts[2] + parts[3];
    float rs = rsqrtf(tot * (1.f / DM) + EPSF);
    orow[t] = v0 * rs * w[t];
    orow[t + 256] = v1 * rs * w[t + 256];
}

// ------------------------------------------------- generic fused f32 GEMM
// C[M,N] = epi( A[M,K] @ W[K,N] + bias[N] )
// 64x64 tile, 256 threads, 4x4 per thread.
template <int EPI>
__global__ __launch_bounds__(256) void gemm_f32(
    const float* __restrict__ A, const float* __restrict__ W,
    const float* __restrict__ bias, float* __restrict__ C,
    const float* __restrict__ uptr, const float* __restrict__ resid,
    const float* __restrict__ bcv, int M, int N, int K) {
    __shared__ float As[16][64];  // [k][m]
    __shared__ float Bs[16][64];  // [k][n]
    int n0 = blockIdx.x * 64, m0 = blockIdx.y * 64;
    int t = threadIdx.x;
    int tx = t & 15, ty = t >> 4;
    int ar = t >> 2, aq = t & 3;
    int br = t >> 4, bq = t & 15;
    float acc[4][4] = {};
    for (int k0 = 0; k0 < K; k0 += 16) {
        float4 av = *(const float4*)(A + (size_t)(m0 + ar) * K + k0 + aq * 4);
        float4 bv = *(const float4*)(W + (size_t)(k0 + br) * N + n0 + bq * 4);
        __syncthreads();
        As[aq * 4 + 0][ar] = av.x;
        As[aq * 4 + 1][ar] = av.y;
        As[aq * 4 + 2][ar] = av.z;
        As[aq * 4 + 3][ar] = av.w;
        *(float4*)&Bs[br][bq * 4] = bv;
        __syncthreads();
#pragma unroll
        for (int kk = 0; kk < 16; ++kk) {
            float4 a = *(const float4*)&As[kk][ty * 4];
            float4 b = *(const float4*)&Bs[kk][tx * 4];
            float aa[4] = {a.x, a.y, a.z, a.w};
            float bb[4] = {b.x, b.y, b.z, b.w};
#pragma unroll
            for (int i = 0; i < 4; ++i)
#pragma unroll
                for (int j = 0; j < 4; ++j) acc[i][j] += aa[i] * bb[j];
        }
    }
    int m = m0 + ty * 4, n = n0 + tx * 4;
    float4 bias4 = *(const float4*)(bias + n);
    float bb[4] = {bias4.x, bias4.y, bias4.z, bias4.w};
#pragma unroll
    for (int i = 0; i < 4; ++i) {
        size_t ro = (size_t)(m + i) * N + n;
#pragma unroll
        for (int j = 0; j < 4; ++j) {
            float c = acc[i][j] + bb[j];
            if (EPI == EPI_NONE) {
                C[ro + j] = c;
            } else if (EPI == EPI_SILU) {
                C[ro + j] = c * sigmoidf_(c);
            } else if (EPI == EPI_SSM) {
                // delta = softplus(c); xs = u*delta*bc; out = resid*silu(xs)
                float sp = (c > 20.f) ? c : log1pf(__expf(c));
                float xs = uptr[ro + j] * sp * bcv[m + i];
                C[ro + j] = resid[ro + j] * (xs * sigmoidf_(xs));
            } else {  // EPI_OUT: final result, float32 store
                C[ro + j] = c;
            }
        }
    }
}

// --------------------------------------------------------------- conv1d
// out[b,o,h] = silu( sum_{i,k} cw[o,i,k]*xp[b,i,h+k-1] + cb[o] )
__global__ __launch_bounds__(256) void conv_k(
    const float* __restrict__ xp, const float* __restrict__ cw,
    const float* __restrict__ cb, float* __restrict__ out) {
    __shared__ float Ws[3][16][64];  // [k][i][o]
    __shared__ float Xs[16][68];     // [i][h0-1 .. h0+64]
    int b = blockIdx.z;
    int n0 = blockIdx.x * 64;  // h (spatial = 2d)
    int m0 = blockIdx.y * 64;  // o (channels = seq)
    int t = threadIdx.x;
    int tx = t & 15, ty = t >> 4;
    const float* xpb = xp + (size_t)b * SEQ * D2;
    float acc[4][4] = {};
    for (int i0 = 0; i0 < SEQ; i0 += 16) {
        __syncthreads();
        {
            int c = t & 15, r0 = (t >> 4) << 2;
#pragma unroll
            for (int p = 0; p < 4; ++p) {
                int r = r0 + p;
                const float* wp =
                    cw + (size_t)(m0 + r) * (SEQ * 3) + (size_t)(i0 + c) * 3;
                Ws[0][c][r] = wp[0];
                Ws[1][c][r] = wp[1];
                Ws[2][c][r] = wp[2];
            }
            int xr = t >> 4, xc = t & 15;
            const float* xrow = xpb + (size_t)(i0 + xr) * D2;
            float4 xv = *(const float4*)(xrow + n0 + xc * 4);
            Xs[xr][1 + xc * 4 + 0] = xv.x;
            Xs[xr][1 + xc * 4 + 1] = xv.y;
            Xs[xr][1 + xc * 4 + 2] = xv.z;
            Xs[xr][1 + xc * 4 + 3] = xv.w;
            if (xc == 0) Xs[xr][0] = (n0 > 0) ? xrow[n0 - 1] : 0.f;
            if (xc == 1) Xs[xr][65] = (n0 + 64 < D2) ? xrow[n0 + 64] : 0.f;
        }
        __syncthreads();
#pragma unroll
        for (int kk = 0; kk < 16; ++kk) {
            float xv[6];
#pragma unroll
            for (int jj = 0; jj < 6; ++jj) xv[jj] = Xs[kk][tx * 4 + jj];
#pragma unroll
            for (int k = 0; k < 3; ++k) {
                float4 a = *(const float4*)&Ws[k][kk][ty * 4];
                float aa[4] = {a.x, a.y, a.z, a.w};
#pragma unroll
                for (int i = 0; i < 4; ++i)
#pragma unroll
                    for (int j = 0; j < 4; ++j) acc[i][j] += aa[i] * xv[j + k];
            }
        }
    }
    size_t outb = (size_t)b * SEQ * D2;
#pragma unroll
    for (int i = 0; i < 4; ++i) {
        int m = m0 + ty * 4 + i;
        float bias = cb[m];
        size_t ro = outb + (size_t)m * D2 + n0 + tx * 4;
#pragma unroll
        for (int j = 0; j < 4; ++j) {
            float c = acc[i][j] + bias;
            out[ro + j] = c * sigmoidf_(c);
        }
    }
}

// ------------------------------------------------------------- B,C -> bc
// bc[m] = sum_n (u@fc2_w + fc2_b)[m,n] * (u@fc3_w + fc3_b)[m,n]
__global__ __launch_bounds__(256) void bc_k(
    const float* __restrict__ u, const float* __restrict__ w2,
    const float* __restrict__ b2, const float* __restrict__ w3,
    const float* __restrict__ b3, float* __restrict__ bc) {
    int wave = threadIdx.x >> 6, lane = threadIdx.x & 63;
    int row = blockIdx.x * 4 + wave;
    const float* ur = u + (size_t)row * D2;
    float acc2[16] = {}, acc3[16] = {};
    for (int it = 0; it < 16; ++it) {
        int k = it * 64 + lane;
        float v = ur[k];
        const float4* w2r = (const float4*)(w2 + (size_t)k * NSTATE);
        const float4* w3r = (const float4*)(w3 + (size_t)k * NSTATE);
#pragma unroll
        for (int q = 0; q < 4; ++q) {
            float4 a = w2r[q], c = w3r[q];
            acc2[q * 4 + 0] += v * a.x;
            acc2[q * 4 + 1] += v * a.y;
            acc2[q * 4 + 2] += v * a.z;
            acc2[q * 4 + 3] += v * a.w;
            acc3[q * 4 + 0] += v * c.x;
            acc3[q * 4 + 1] += v * c.y;
            acc3[q * 4 + 2] += v * c.z;
            acc3[q * 4 + 3] += v * c.w;
        }
    }
#pragma unroll
    for (int off = 32; off; off >>= 1) {
#pragma unroll
        for (int n = 0; n < 16; ++n) {
            acc2[n] += __shfl_xor(acc2[n], off, 64);
            acc3[n] += __shfl_xor(acc3[n], off, 64);
        }
    }
    if (lane == 0) {
        float s = 0.f;
#pragma unroll
        for (int n = 0; n < 16; ++n)
            s += (acc2[n] + b2[n]) * (acc3[n] + b3[n]);
        bc[row] = s;
    }
}

// ----------------------------------------------------------------- launch
extern "C" void kernel_launch(void* const* d_in, const int* in_sizes, int n_in,
                              void* d_out, int out_size, void* d_ws,
                              size_t ws_size, hipStream_t stream) {
    const float* x = (const float*)d_in[0];
    const float* norm_w = (const float*)d_in[1];
    const float* inp_w = (const float*)d_in[2];
    const float* inp_b = (const float*)d_in[3];
    const float* conv_w = (const float*)d_in[4];
    const float* conv_b = (const float*)d_in[5];
    const float* convlin_w = (const float*)d_in[6];
    const float* convlin_b = (const float*)d_in[7];
    const float* fc1_w = (const float*)d_in[8];
    const float* fc1_b = (const float*)d_in[9];
    const float* fc2_w = (const float*)d_in[10];
    const float* fc2_b = (const float*)d_in[11];
    const float* fc3_w = (const float*)d_in[12];
    const float* fc3_b = (const float*)d_in[13];
    const float* D_w = (const float*)d_in[14];
    const float* D_b = (const float*)d_in[15];
    const float* out_w = (const float*)d_in[16];
    const float* out_b = (const float*)d_in[17];
    float* out = (float*)d_out;  // reference output dtype is float32

    float* ws = (float*)d_ws;
    float* xn = ws;                          // ROWS*DM
    float* bufA = xn + (size_t)ROWS * DM;    // ROWS*D2 : x_proj, then u
    float* bufB = bufA + (size_t)ROWS * D2;  // ROWS*D2 : conv_silu/resid/act
    float* bcb = bufB + (size_t)ROWS * D2;   // ROWS

    // 1. xn = rmsnorm(x) * norm_w
    rmsnorm_k<<<ROWS, 256, 0, stream>>>(x, norm_w, xn);
    // 2. x_proj = xn @ inp_w + inp_b          -> bufA
    gemm_f32<EPI_NONE><<<dim3(D2 / 64, ROWS / 64), 256, 0, stream>>>(
        xn, inp_w, inp_b, bufA, nullptr, nullptr, nullptr, ROWS, D2, DM);
    // 3. conv + bias + silu                   -> bufB
    conv_k<<<dim3(D2 / 64, SEQ / 64, BATCH), 256, 0, stream>>>(bufA, conv_w,
                                                               conv_b, bufB);
    // 4. u = conv_silu @ convlin_w + b        -> bufA
    gemm_f32<EPI_NONE><<<dim3(D2 / 64, ROWS / 64), 256, 0, stream>>>(
        bufB, convlin_w, convlin_b, bufA, nullptr, nullptr, nullptr, ROWS, D2,
        D2);
    // 5. bc[m] = sum((u@fc2+b2)*(u@fc3+b3))   -> bcb
    bc_k<<<ROWS / 4, 256, 0, stream>>>(bufA, fc2_w, fc2_b, fc3_w, fc3_b, bcb);
    // 6. resid = silu(xn @ D_w + D_b)         -> bufB
    gemm_f32<EPI_SILU><<<dim3(D2 / 64, ROWS / 64), 256, 0, stream>>>(
        xn, D_w, D_b, bufB, nullptr, nullptr, nullptr, ROWS, D2, DM);
    // 7. delta GEMM + fused ssm tail          -> bufB (in place)
    gemm_f32<EPI_SSM><<<dim3(D2 / 64, ROWS / 64), 256, 0, stream>>>(
        bufA, fc1_w, fc1_b, bufB, bufA, bufB, bcb, ROWS, D2, D2);
    // 8. out = act @ out_w + out_b (f32)      -> d_out
    gemm_f32<EPI_OUT><<<dim3(DM / 64, ROWS / 64), 256, 0, stream>>>(
        bufB, out_w, out_b, out, nullptr, nullptr, nullptr, ROWS, DM, D2);
}

// Round 4
// 318.964 us; speedup vs baseline: 5.4589x; 5.4589x over previous
//
#include <hip/hip_runtime.h>
#include <hip/hip_bf16.h>

#define SEQ 1024
#define DM 512
#define D2 1024
#define NSTATE 16
#define BATCH 8
#define ROWS (BATCH * SEQ)
#define EPSF 1e-5f

typedef __attribute__((ext_vector_type(8))) short bf16x8;
typedef __attribute__((ext_vector_type(4))) float f32x4;

#define AS1 __attribute__((address_space(1)))
#define AS3 __attribute__((address_space(3)))

__device__ __forceinline__ void gll16(const void* g, void* l) {
    __builtin_amdgcn_global_load_lds(
        (const AS1 unsigned int*)(uintptr_t)g,
        (AS3 unsigned int*)(unsigned int)(uintptr_t)l, 16, 0, 0);
}

__device__ __forceinline__ float sigmoidf_(float x) {
    return 1.f / (1.f + __expf(-x));
}
__device__ __forceinline__ unsigned short f2bf(float f) {
    __hip_bfloat16 h = __float2bfloat16(f);
    unsigned short r;
    __builtin_memcpy(&r, &h, 2);
    return r;
}

// ---------------------------------------------------- weight prep kernels
// f32 [R][C] -> bf16 [C][R]
__global__ __launch_bounds__(256) void tcvt_k(const float* __restrict__ src,
                                              __hip_bfloat16* __restrict__ dst,
                                              int R, int C) {
    __shared__ float tile[32][33];
    int c0 = blockIdx.x * 32, r0 = blockIdx.y * 32;
    int tx = threadIdx.x & 31, ty = threadIdx.x >> 5;  // 8 rows of 32
#pragma unroll
    for (int p = 0; p < 4; ++p) {
        int r = r0 + ty + p * 8, c = c0 + tx;
        if (r < R && c < C) tile[ty + p * 8][tx] = src[(size_t)r * C + c];
    }
    __syncthreads();
#pragma unroll
    for (int p = 0; p < 4; ++p) {
        int c = c0 + ty + p * 8, r = r0 + tx;
        if (r < R && c < C)
            dst[(size_t)c * R + r] = __float2bfloat16(tile[tx][ty + p * 8]);
    }
}

// conv_w [o][i][3] f32 -> wk [3][o][i] bf16
__global__ __launch_bounds__(256) void convw_k(const float* __restrict__ cw,
                                               __hip_bfloat16* __restrict__ wk) {
    int idx = blockIdx.x * 256 + threadIdx.x;  // o*SEQ + i
    float a = cw[(size_t)idx * 3 + 0];
    float b = cw[(size_t)idx * 3 + 1];
    float c = cw[(size_t)idx * 3 + 2];
    wk[idx] = __float2bfloat16(a);
    wk[(size_t)SEQ * SEQ + idx] = __float2bfloat16(b);
    wk[(size_t)2 * SEQ * SEQ + idx] = __float2bfloat16(c);
}

// ---------------------------------------------------------------- rmsnorm
__global__ __launch_bounds__(256) void rmsnorm_k(
    const float* __restrict__ x, const float* __restrict__ w,
    __hip_bfloat16* __restrict__ o) {
    int row = blockIdx.x;
    const float* xr = x + (size_t)row * DM;
    __hip_bfloat16* orow = o + (size_t)row * DM;
    int t = threadIdx.x;
    float v0 = xr[t];
    float v1 = xr[t + 256];
    float ss = v0 * v0 + v1 * v1;
#pragma unroll
    for (int off = 32; off; off >>= 1) ss += __shfl_down(ss, off, 64);
    __shared__ float parts[4];
    if ((t & 63) == 0) parts[t >> 6] = ss;
    __syncthreads();
    float tot = parts[0] + parts[1] + parts[2] + parts[3];
    float rs = rsqrtf(tot * (1.f / DM) + EPSF);
    orow[t] = __float2bfloat16(v0 * rs * w[t]);
    orow[t + 256] = __float2bfloat16(v1 * rs * w[t + 256]);
}

// ------------------------------------------------------ MFMA bf16 GEMM
// C[M,N] = epi( A[M,K] @ Bt[N,K]^T + bias[N] )
// 128x128 tile, 4 waves (2x2, 64x64/wave), BK=32, 16x16x32 MFMA.
// EPI: 0 = transposed bf16 (x_proj -> Xt[b][n][m%SEQ]); 1 = bf16;
//      2 = silu->bf16; 3 = ssm tail->bf16; 4 = f32.
template <int EPI>
__global__ __launch_bounds__(256) void mgemm(
    const __hip_bfloat16* __restrict__ A, const __hip_bfloat16* __restrict__ Bt,
    const float* __restrict__ bias, void* __restrict__ outp,
    const __hip_bfloat16* __restrict__ uptr,
    const __hip_bfloat16* __restrict__ resid, const float* __restrict__ bcv,
    int M, int N, int K) {
    __shared__ __align__(16) __hip_bfloat16 As[128 * 32];
    __shared__ __align__(16) __hip_bfloat16 Bs[128 * 32];
    const int n0 = blockIdx.x * 128, m0 = blockIdx.y * 128;
    const int t = threadIdx.x, lane = t & 63, w = t >> 6;
    const int wr = w >> 1, wc = w & 1;
    const int l15 = lane & 15, l4 = lane >> 4;
    f32x4 acc[4][4] = {};
    for (int k0 = 0; k0 < K; k0 += 32) {
        __syncthreads();
#pragma unroll
        for (int p = 0; p < 2; ++p) {
            int blk = p * 256 + t;  // 16B block, = base + lane
            int row = blk >> 2;
            int cbl = (blk & 3) ^ ((row >> 1) & 3);  // pre-swizzled source
            gll16(A + (size_t)(m0 + row) * K + k0 + cbl * 8,
                  &As[(p * 256 + w * 64) * 8]);
            gll16(Bt + (size_t)(n0 + row) * K + k0 + cbl * 8,
                  &Bs[(p * 256 + w * 64) * 8]);
        }
        __syncthreads();
        bf16x8 af[4], bfv[4];
#pragma unroll
        for (int i = 0; i < 4; ++i) {
            int ra = wr * 64 + i * 16 + l15;
            af[i] = *(const bf16x8*)&As[(ra * 4 + (l4 ^ ((ra >> 1) & 3))) * 8];
            int rb = wc * 64 + i * 16 + l15;
            bfv[i] = *(const bf16x8*)&Bs[(rb * 4 + (l4 ^ ((rb >> 1) & 3))) * 8];
        }
#pragma unroll
        for (int i = 0; i < 4; ++i)
#pragma unroll
            for (int j = 0; j < 4; ++j)
                acc[i][j] = __builtin_amdgcn_mfma_f32_16x16x32_bf16(
                    af[i], bfv[j], acc[i][j], 0, 0, 0);
    }
    const int mb = m0 + wr * 64, nb = n0 + wc * 64;
#pragma unroll
    for (int i = 0; i < 4; ++i) {
#pragma unroll
        for (int j = 0; j < 4; ++j) {
            int ngl = nb + j * 16 + l15;
            float bj = bias[ngl];
            if (EPI == 0) {
                int b = m0 >> 10;
                int ibase = (mb & (SEQ - 1)) + i * 16 + l4 * 4;
                ushort4 pk;
                pk.x = f2bf(acc[i][j][0] + bj);
                pk.y = f2bf(acc[i][j][1] + bj);
                pk.z = f2bf(acc[i][j][2] + bj);
                pk.w = f2bf(acc[i][j][3] + bj);
                *(ushort4*)((__hip_bfloat16*)outp +
                            ((size_t)b * D2 + ngl) * SEQ + ibase) = pk;
            } else {
#pragma unroll
                for (int r = 0; r < 4; ++r) {
                    int mg = mb + i * 16 + l4 * 4 + r;
                    size_t ro = (size_t)mg * N + ngl;
                    float c = acc[i][j][r] + bj;
                    if (EPI == 1) {
                        ((__hip_bfloat16*)outp)[ro] = __float2bfloat16(c);
                    } else if (EPI == 2) {
                        ((__hip_bfloat16*)outp)[ro] =
                            __float2bfloat16(c * sigmoidf_(c));
                    } else if (EPI == 3) {
                        float sp = (c > 20.f) ? c : log1pf(__expf(c));
                        float xs = __bfloat162float(uptr[ro]) * sp * bcv[mg];
                        float v = __bfloat162float(resid[ro]) *
                                  (xs * sigmoidf_(xs));
                        ((__hip_bfloat16*)outp)[ro] = __float2bfloat16(v);
                    } else {
                        ((float*)outp)[ro] = c;
                    }
                }
            }
        }
    }
}

// ------------------------------------------------------------ conv (MFMA)
// out[z,o,h] = silu( sum_tap sum_i wk[tap][o][i] * Xt[z][h+tap-1][i] + cb[o] )
__global__ __launch_bounds__(256) void conv_mfma(
    const __hip_bfloat16* __restrict__ wk,  // [3][SEQ][SEQ]
    const __hip_bfloat16* __restrict__ Xt,  // [B][D2][SEQ]
    const float* __restrict__ cb, __hip_bfloat16* __restrict__ outp) {
    __shared__ __align__(16) __hip_bfloat16 Ws[3][128 * 32];
    __shared__ __align__(16) __hip_bfloat16 Xs[130 * 32];
    const int z = blockIdx.z;
    const int n0 = blockIdx.x * 128;  // h
    const int m0 = blockIdx.y * 128;  // o
    const int t = threadIdx.x, lane = t & 63, w = t >> 6;
    const int wr = w >> 1, wc = w & 1;
    const int l15 = lane & 15, l4 = lane >> 4;
    const __hip_bfloat16* Xtb = Xt + (size_t)z * D2 * SEQ;
    f32x4 acc[4][4] = {};
    for (int k0 = 0; k0 < SEQ; k0 += 32) {
        __syncthreads();
#pragma unroll
        for (int p = 0; p < 2; ++p) {
            int blk = p * 256 + t;
            int row = blk >> 2;
            int cbl = (blk & 3) ^ ((row >> 1) & 3);
#pragma unroll
            for (int tp = 0; tp < 3; ++tp)
                gll16(wk + (size_t)tp * SEQ * SEQ + (size_t)(m0 + row) * SEQ +
                          k0 + cbl * 8,
                      &Ws[tp][(p * 256 + w * 64) * 8]);
            // B main: LDS rows 1..128 <-> h = n0-1+row2 in [n0, n0+127]
            int blk2 = 4 + p * 256 + t;
            int row2 = blk2 >> 2;
            int cbl2 = (blk2 & 3) ^ ((row2 >> 1) & 3);
            gll16(Xtb + (size_t)(n0 - 1 + row2) * SEQ + k0 + cbl2 * 8,
                  &Xs[(4 + p * 256 + w * 64) * 8]);
        }
        // halo rows 0 and 129 (h = n0-1, n0+128), zero-padded at edges
        if (t < 8) {
            int row = (t < 4) ? 0 : 129;
            int cbp = t & 3;
            int cbl = cbp ^ ((row >> 1) & 3);
            int h = n0 - 1 + row;
            uint4 v = make_uint4(0u, 0u, 0u, 0u);
            if (h >= 0 && h < D2)
                v = *(const uint4*)(Xtb + (size_t)h * SEQ + k0 + cbl * 8);
            *(uint4*)&Xs[(row * 4 + cbp) * 8] = v;
        }
        __syncthreads();
        bf16x8 aw[3][4];
#pragma unroll
        for (int tp = 0; tp < 3; ++tp)
#pragma unroll
            for (int i = 0; i < 4; ++i) {
                int ra = wr * 64 + i * 16 + l15;
                aw[tp][i] = *(const bf16x8*)&Ws[tp][(ra * 4 +
                                                    (l4 ^ ((ra >> 1) & 3))) *
                                                   8];
            }
#pragma unroll
        for (int j = 0; j < 4; ++j) {
#pragma unroll
            for (int tp = 0; tp < 3; ++tp) {
                int rb = wc * 64 + j * 16 + l15 + tp;  // LDS row = nl + tap
                bf16x8 bv =
                    *(const bf16x8*)&Xs[(rb * 4 + (l4 ^ ((rb >> 1) & 3))) * 8];
#pragma unroll
                for (int i = 0; i < 4; ++i)
                    acc[i][j] = __builtin_amdgcn_mfma_f32_16x16x32_bf16(
                        aw[tp][i], bv, acc[i][j], 0, 0, 0);
            }
        }
    }
    const int mb = m0 + wr * 64, nb = n0 + wc * 64;
    size_t ob = (size_t)z * SEQ * D2;
#pragma unroll
    for (int i = 0; i < 4; ++i)
#pragma unroll
        for (int j = 0; j < 4; ++j)
#pragma unroll
            for (int r = 0; r < 4; ++r) {
                int mg = mb + i * 16 + l4 * 4 + r;
                int ng = nb + j * 16 + l15;
                float c = acc[i][j][r] + cb[mg];
                outp[ob + (size_t)mg * D2 + ng] =
                    __float2bfloat16(c * sigmoidf_(c));
            }
}

// ------------------------------------------------------------- B,C -> bc
__global__ __launch_bounds__(256) void bc_k(
    const __hip_bfloat16* __restrict__ u, const float* __restrict__ w2,
    const float* __restrict__ b2, const float* __restrict__ w3,
    const float* __restrict__ b3, float* __restrict__ bc) {
    int wave = threadIdx.x >> 6, lane = threadIdx.x & 63;
    int row = blockIdx.x * 4 + wave;
    const __hip_bfloat16* ur = u + (size_t)row * D2;
    float acc2[16] = {}, acc3[16] = {};
    for (int it = 0; it < 16; ++it) {
        int k = it * 64 + lane;
        float v = __bfloat162float(ur[k]);
        const float4* w2r = (const float4*)(w2 + (size_t)k * NSTATE);
        const float4* w3r = (const float4*)(w3 + (size_t)k * NSTATE);
#pragma unroll
        for (int q = 0; q < 4; ++q) {
            float4 a = w2r[q], c = w3r[q];
            acc2[q * 4 + 0] += v * a.x;
            acc2[q * 4 + 1] += v * a.y;
            acc2[q * 4 + 2] += v * a.z;
            acc2[q * 4 + 3] += v * a.w;
            acc3[q * 4 + 0] += v * c.x;
            acc3[q * 4 + 1] += v * c.y;
            acc3[q * 4 + 2] += v * c.z;
            acc3[q * 4 + 3] += v * c.w;
        }
    }
#pragma unroll
    for (int off = 32; off; off >>= 1) {
#pragma unroll
        for (int n = 0; n < 16; ++n) {
            acc2[n] += __shfl_xor(acc2[n], off, 64);
            acc3[n] += __shfl_xor(acc3[n], off, 64);
        }
    }
    if (lane == 0) {
        float s = 0.f;
#pragma unroll
        for (int n = 0; n < 16; ++n)
            s += (acc2[n] + b2[n]) * (acc3[n] + b3[n]);
        bc[row] = s;
    }
}

// ----------------------------------------------------------------- launch
extern "C" void kernel_launch(void* const* d_in, const int* in_sizes, int n_in,
                              void* d_out, int out_size, void* d_ws,
                              size_t ws_size, hipStream_t stream) {
    const float* x = (const float*)d_in[0];
    const float* norm_w = (const float*)d_in[1];
    const float* inp_w = (const float*)d_in[2];
    const float* inp_b = (const float*)d_in[3];
    const float* conv_w = (const float*)d_in[4];
    const float* conv_b = (const float*)d_in[5];
    const float* convlin_w = (const float*)d_in[6];
    const float* convlin_b = (const float*)d_in[7];
    const float* fc1_w = (const float*)d_in[8];
    const float* fc1_b = (const float*)d_in[9];
    const float* fc2_w = (const float*)d_in[10];
    const float* fc2_b = (const float*)d_in[11];
    const float* fc3_w = (const float*)d_in[12];
    const float* fc3_b = (const float*)d_in[13];
    const float* D_w = (const float*)d_in[14];
    const float* D_b = (const float*)d_in[15];
    const float* out_w = (const float*)d_in[16];
    const float* out_b = (const float*)d_in[17];
    float* out = (float*)d_out;

    __hip_bfloat16* xnb = (__hip_bfloat16*)d_ws;            // [ROWS][DM]
    __hip_bfloat16* xt = xnb + (size_t)ROWS * DM;           // [B][D2][SEQ]
    __hip_bfloat16* cvo = xt + (size_t)BATCH * D2 * SEQ;    // conv out / act
    __hip_bfloat16* u = cvo + (size_t)ROWS * D2;            // [ROWS][D2]
    __hip_bfloat16* resid = u + (size_t)ROWS * D2;          // [ROWS][D2]
    __hip_bfloat16* inpT = resid + (size_t)ROWS * D2;       // [D2][DM]
    __hip_bfloat16* clT = inpT + (size_t)D2 * DM;           // [D2][D2]
    __hip_bfloat16* fc1T = clT + (size_t)D2 * D2;           // [D2][D2]
    __hip_bfloat16* DT = fc1T + (size_t)D2 * D2;            // [D2][DM]
    __hip_bfloat16* outT = DT + (size_t)D2 * DM;            // [DM][D2]
    __hip_bfloat16* wk = outT + (size_t)DM * D2;            // [3][SEQ][SEQ]
    float* bcb = (float*)(wk + (size_t)3 * SEQ * SEQ);      // [ROWS]

    // weight prep
    tcvt_k<<<dim3(D2 / 32, DM / 32), 256, 0, stream>>>(inp_w, inpT, DM, D2);
    tcvt_k<<<dim3(D2 / 32, D2 / 32), 256, 0, stream>>>(convlin_w, clT, D2, D2);
    tcvt_k<<<dim3(D2 / 32, D2 / 32), 256, 0, stream>>>(fc1_w, fc1T, D2, D2);
    tcvt_k<<<dim3(D2 / 32, DM / 32), 256, 0, stream>>>(D_w, DT, DM, D2);
    tcvt_k<<<dim3(DM / 32, D2 / 32), 256, 0, stream>>>(out_w, outT, D2, DM);
    convw_k<<<SEQ * SEQ / 256, 256, 0, stream>>>(conv_w, wk);
    // 1. xn = rmsnorm(x) (bf16)
    rmsnorm_k<<<ROWS, 256, 0, stream>>>(x, norm_w, xnb);
    // 2. x_proj = xn @ inp_w + b   -> transposed: Xt[b][h][i]
    mgemm<0><<<dim3(D2 / 128, ROWS / 128), 256, 0, stream>>>(
        xnb, inpT, inp_b, xt, nullptr, nullptr, nullptr, ROWS, D2, DM);
    // 3. conv + bias + silu        -> cvo[b][o][h]
    conv_mfma<<<dim3(D2 / 128, SEQ / 128, BATCH), 256, 0, stream>>>(
        wk, xt, conv_b, cvo);
    // 4. u = cvo @ convlin + b     -> u (bf16)
    mgemm<1><<<dim3(D2 / 128, ROWS / 128), 256, 0, stream>>>(
        cvo, clT, convlin_b, u, nullptr, nullptr, nullptr, ROWS, D2, D2);
    // 5. bc
    bc_k<<<ROWS / 4, 256, 0, stream>>>(u, fc2_w, fc2_b, fc3_w, fc3_b, bcb);
    // 6. resid = silu(xn @ D_w + b)
    mgemm<2><<<dim3(D2 / 128, ROWS / 128), 256, 0, stream>>>(
        xnb, DT, D_b, resid, nullptr, nullptr, nullptr, ROWS, D2, DM);
    // 7. delta GEMM + ssm tail     -> act (reuses cvo)
    mgemm<3><<<dim3(D2 / 128, ROWS / 128), 256, 0, stream>>>(
        u, fc1T, fc1_b, cvo, u, resid, bcb, ROWS, D2, D2);
    // 8. out = act @ out_w + out_b (f32)
    mgemm<4><<<dim3(DM / 128, ROWS / 128), 256, 0, stream>>>(
        cvo, outT, out_b, out, nullptr, nullptr, nullptr, ROWS, DM, D2);
}